// Round 1
// baseline (943.858 us; speedup 1.0000x reference)
//
#include <hip/hip_runtime.h>
#include <math.h>

#define TB1 4
#define TB2 16

__device__ __forceinline__ float4 ldg4(const float* p) { return *(const float4*)p; }

// ---------------------------------------------------------------------------
// Kernel 1: up router + up experts + gelu  ->  h (fp32 [N][4096]) in workspace
// ---------------------------------------------------------------------------
__global__ __launch_bounds__(256, 2) void up_kernel(
    const float* __restrict__ x,        // [N][1024]
    const float* __restrict__ Wup,      // [64][1024]
    const float* __restrict__ Aup,      // [64][64][32]
    const float* __restrict__ Bup,      // [64][64][32]
    const float* __restrict__ scale_up, // [1]
    const float* __restrict__ bias_up,  // [4096]
    float* __restrict__ h)              // [N][4096]
{
    __shared__ float xs[TB1 * 1024];   // 16 KB
    __shared__ float buf[6912];        // wcs[64*68] | as[64*36]+bs[64*36]+t1[64*36]
    __shared__ float lp[4 * TB1 * 64]; // j-slice partial logits
    __shared__ float logits[TB1 * 64];
    __shared__ int   seli[TB1 * 2];
    __shared__ float selp[TB1 * 2];

    const int tid = threadIdx.x;
    const long long blockTok = (long long)blockIdx.x * TB1;

    // ---- stage x tile (coalesced) ----
    {
        const float* src = x + blockTok * 1024;
#pragma unroll
        for (int q = 0; q < TB1; ++q) {
            int flat = tid * 4 + q * 1024;
            *(float4*)&xs[flat] = ldg4(src + flat);
        }
    }

    // ---- up router: logits[t][e] = x[t] . Wup[e] ----
    float racc[TB1] = {0.f, 0.f, 0.f, 0.f};
    float* wcs = buf; // [64][68]
    const int e = tid & 63, jsl = tid >> 6;
    for (int kc = 0; kc < 1024; kc += 64) {
        __syncthreads();
#pragma unroll
        for (int r = 0; r < 4; ++r) {
            int row = (tid >> 4) + r * 16;
            int col = (tid & 15) * 4;
            *(float4*)&wcs[row * 68 + col] = ldg4(&Wup[row * 1024 + kc + col]);
        }
        __syncthreads();
#pragma unroll
        for (int ks = 0; ks < 4; ++ks) {
            int kk = jsl * 16 + ks * 4;
            float4 w = *(float4*)&wcs[e * 68 + kk];
#pragma unroll
            for (int t = 0; t < TB1; ++t) {
                float4 xv = *(float4*)&xs[t * 1024 + kc + kk];
                racc[t] += w.x * xv.x + w.y * xv.y + w.z * xv.z + w.w * xv.w;
            }
        }
    }
#pragma unroll
    for (int t = 0; t < TB1; ++t) lp[(jsl * TB1 + t) * 64 + e] = racc[t];
    __syncthreads();
    {
        int idx = tid; // TB1*64 = 256 pairs
        logits[idx] = lp[0 * TB1 * 64 + idx] + lp[1 * TB1 * 64 + idx] +
                      lp[2 * TB1 * 64 + idx] + lp[3 * TB1 * 64 + idx];
    }
    __syncthreads();
    if (tid < TB1) {
        const float* lg = &logits[tid * 64];
        float v0 = -1e30f; int i0 = 0;
        for (int q = 0; q < 64; ++q) { float v = lg[q]; if (v > v0) { v0 = v; i0 = q; } }
        float v1 = -1e30f; int i1 = 0;
        for (int q = 0; q < 64; ++q) { if (q == i0) continue; float v = lg[q]; if (v > v1) { v1 = v; i1 = q; } }
        float r = expf(v1 - v0);
        float inv = 1.f / (1.f + r);
        seli[tid * 2] = i0; seli[tid * 2 + 1] = i1;
        selp[tid * 2] = inv; selp[tid * 2 + 1] = r * inv;
    }
    __syncthreads();

    // ---- up experts ----
    float* as_ = buf;          // [64][36]
    float* bs_ = buf + 2304;   // [64][36]
    float* t1_ = buf + 4608;   // [64][36]
    const float sc_up = scale_up[0];

    for (int t = 0; t < TB1; ++t) {
        float acc16[16];
#pragma unroll
        for (int q = 0; q < 16; ++q) acc16[q] = 0.f;

        for (int ke = 0; ke < 2; ++ke) {
            __syncthreads(); // protect as/bs/t1 from previous readers
            int ex = seli[t * 2 + ke];
            float pw = selp[t * 2 + ke];
            {
                const float* A = Aup + ex * 2048;
                const float* B = Bup + ex * 2048;
#pragma unroll
                for (int q = 0; q < 2; ++q) {
                    int flat = tid * 4 + q * 1024;
                    int r = flat >> 5, c = flat & 31;
                    *(float4*)&as_[r * 36 + c] = ldg4(A + flat);
                    *(float4*)&bs_[r * 36 + c] = ldg4(B + flat);
                }
            }
            __syncthreads();
            // T1[o][j] = sum_i A[o][i] * X[i][j]   (X[i][j] = xs[t][i*32+j])
            {
                int o = tid >> 2, j0 = (tid & 3) * 8;
                float s[8] = {0.f, 0.f, 0.f, 0.f, 0.f, 0.f, 0.f, 0.f};
#pragma unroll 8
                for (int i = 0; i < 32; ++i) {
                    float a = as_[o * 36 + i];
                    float4 x0 = *(float4*)&xs[t * 1024 + i * 32 + j0];
                    float4 x1 = *(float4*)&xs[t * 1024 + i * 32 + j0 + 4];
                    s[0] += a * x0.x; s[1] += a * x0.y; s[2] += a * x0.z; s[3] += a * x0.w;
                    s[4] += a * x1.x; s[5] += a * x1.y; s[6] += a * x1.z; s[7] += a * x1.w;
                }
                *(float4*)&t1_[o * 36 + j0]     = make_float4(s[0], s[1], s[2], s[3]);
                *(float4*)&t1_[o * 36 + j0 + 4] = make_float4(s[4], s[5], s[6], s[7]);
            }
            __syncthreads();
            // Y[o][p] += pw * sum_j T1[o][j] * B[p][j]
            {
                int o = tid >> 2, p0 = (tid & 3) * 16;
                float tr[32];
#pragma unroll
                for (int j = 0; j < 32; j += 4) {
                    float4 v = *(float4*)&t1_[o * 36 + j];
                    tr[j] = v.x; tr[j + 1] = v.y; tr[j + 2] = v.z; tr[j + 3] = v.w;
                }
#pragma unroll
                for (int pp = 0; pp < 16; ++pp) {
                    const float* br = &bs_[(p0 + pp) * 36];
                    float d = 0.f;
#pragma unroll
                    for (int j = 0; j < 32; j += 4) {
                        float4 b = *(float4*)&br[j];
                        d += b.x * tr[j] + b.y * tr[j + 1] + b.z * tr[j + 2] + b.w * tr[j + 3];
                    }
                    acc16[pp] += pw * d;
                }
            }
        }
        // epilogue: scale + bias + gelu(erf), coalesced write (flat == tid*16+pp)
        {
            long long tok = blockTok + t;
            float* hrow = h + tok * 4096;
#pragma unroll
            for (int q = 0; q < 4; ++q) {
                float vv[4];
#pragma unroll
                for (int z = 0; z < 4; ++z) {
                    int pp = q * 4 + z;
                    float v = acc16[pp] * sc_up + bias_up[tid * 16 + pp];
                    vv[z] = 0.5f * v * (1.0f + erff(v * 0.70710678118654752f));
                }
                *(float4*)&hrow[tid * 16 + q * 4] = make_float4(vv[0], vv[1], vv[2], vv[3]);
            }
        }
    }
}

// ---------------------------------------------------------------------------
// Kernel 2: down router + down experts  ->  out (fp32 [N][1024])
// ---------------------------------------------------------------------------
__global__ __launch_bounds__(256, 2) void down_kernel(
    const float* __restrict__ h,        // [N][4096]
    const float* __restrict__ Wdn,      // [64][4096]
    const float* __restrict__ Adn,      // [64][32][64]
    const float* __restrict__ Bdn,      // [64][32][64]
    const float* __restrict__ scale_dn, // [1]
    const float* __restrict__ bias_dn,  // [1024]
    float* __restrict__ out)            // [N][1024]
{
    __shared__ float wcs[64 * 68];   // router W chunk | later xls[64][68]
    __shared__ float rbuf[6528];     // hcs[16*68]+lp[4096] | adl+bdl+t1l (each 32*68)
    __shared__ float logits[TB2 * 64];
    __shared__ int   seli[TB2 * 2];
    __shared__ float selp[TB2 * 2];

    const int tid = threadIdx.x;
    const long long tokbase = (long long)blockIdx.x * TB2;
    float* hcs = rbuf;          // [16][68]
    float* lp  = rbuf + 1088;   // [4][16][64]

    // ---- down router ----
    float racc[TB2];
#pragma unroll
    for (int t = 0; t < TB2; ++t) racc[t] = 0.f;
    const int e = tid & 63, jsl = tid >> 6;

    for (int kc = 0; kc < 4096; kc += 64) {
        __syncthreads();
#pragma unroll
        for (int r = 0; r < 4; ++r) {
            int row = (tid >> 4) + r * 16;
            int col = (tid & 15) * 4;
            *(float4*)&wcs[row * 68 + col] = ldg4(&Wdn[row * 4096 + kc + col]);
        }
        {
            int k = tid & 63;
#pragma unroll
            for (int q = 0; q < 4; ++q) {
                int t = (tid >> 6) + q * 4;
                hcs[t * 68 + k] = h[(tokbase + t) * 4096 + kc + k];
            }
        }
        __syncthreads();
#pragma unroll
        for (int ks = 0; ks < 4; ++ks) {
            int kk = jsl * 16 + ks * 4;
            float4 w = *(float4*)&wcs[e * 68 + kk];
#pragma unroll
            for (int t = 0; t < TB2; ++t) {
                float4 hv = *(float4*)&hcs[t * 68 + kk];
                racc[t] += w.x * hv.x + w.y * hv.y + w.z * hv.z + w.w * hv.w;
            }
        }
    }
#pragma unroll
    for (int t = 0; t < TB2; ++t) lp[(jsl * TB2 + t) * 64 + e] = racc[t];
    __syncthreads();
#pragma unroll
    for (int q = 0; q < 4; ++q) {
        int pair = tid + q * 256;
        logits[pair] = lp[0 * 1024 + pair] + lp[1 * 1024 + pair] +
                       lp[2 * 1024 + pair] + lp[3 * 1024 + pair];
    }
    __syncthreads();
    if (tid < TB2) {
        const float* lg = &logits[tid * 64];
        float v0 = -1e30f; int i0 = 0;
        for (int q = 0; q < 64; ++q) { float v = lg[q]; if (v > v0) { v0 = v; i0 = q; } }
        float v1 = -1e30f; int i1 = 0;
        for (int q = 0; q < 64; ++q) { if (q == i0) continue; float v = lg[q]; if (v > v1) { v1 = v; i1 = q; } }
        float r = expf(v1 - v0);
        float inv = 1.f / (1.f + r);
        seli[tid * 2] = i0; seli[tid * 2 + 1] = i1;
        selp[tid * 2] = inv; selp[tid * 2 + 1] = r * inv;
    }
    __syncthreads();

    // ---- down experts ----
    float* xls = wcs;              // [64][68]
    float* adl = rbuf;             // [32][68]
    float* bdl = rbuf + 2176;      // [32][68]
    float* t1l = rbuf + 4352;      // [32][68]
    const float sc_dn = scale_dn[0];

    for (int t = 0; t < TB2; ++t) {
        long long tok = tokbase + t;
        __syncthreads();
        // stage X = h[tok] as [64][68]
#pragma unroll
        for (int q = 0; q < 4; ++q) {
            int flat = tid * 4 + q * 1024;
            int i = flat >> 6, c = flat & 63;
            *(float4*)&xls[i * 68 + c] = ldg4(&h[tok * 4096 + flat]);
        }
        float acc4[4] = {0.f, 0.f, 0.f, 0.f};
        for (int ke = 0; ke < 2; ++ke) {
            __syncthreads(); // xls ready (ke 0); adl/bdl/t1l free of readers
            int ex = seli[t * 2 + ke];
            float pw = selp[t * 2 + ke];
            {
                const float* A = Adn + ex * 2048;
                const float* B = Bdn + ex * 2048;
#pragma unroll
                for (int q = 0; q < 2; ++q) {
                    int flat = tid * 4 + q * 1024;
                    int r = flat >> 6, c = flat & 63;
                    *(float4*)&adl[r * 68 + c] = ldg4(A + flat);
                    *(float4*)&bdl[r * 68 + c] = ldg4(B + flat);
                }
            }
            __syncthreads();
            // T1[o][j] = sum_i A[o][i] * X[i][j]   (o<32, j<64)
            {
                int o = tid >> 3, j0 = (tid & 7) * 8;
                float s[8] = {0.f, 0.f, 0.f, 0.f, 0.f, 0.f, 0.f, 0.f};
#pragma unroll 4
                for (int i = 0; i < 64; ++i) {
                    float a = adl[o * 68 + i];
                    float4 x0 = *(float4*)&xls[i * 68 + j0];
                    float4 x1 = *(float4*)&xls[i * 68 + j0 + 4];
                    s[0] += a * x0.x; s[1] += a * x0.y; s[2] += a * x0.z; s[3] += a * x0.w;
                    s[4] += a * x1.x; s[5] += a * x1.y; s[6] += a * x1.z; s[7] += a * x1.w;
                }
                *(float4*)&t1l[o * 68 + j0]     = make_float4(s[0], s[1], s[2], s[3]);
                *(float4*)&t1l[o * 68 + j0 + 4] = make_float4(s[4], s[5], s[6], s[7]);
            }
            __syncthreads();
            // Y[o][p] += pw * sum_j T1[o][j] * B[p][j]   (o<32, p<32)
            {
                int o = tid >> 3, p0 = (tid & 7) * 4;
                float tr[64];
#pragma unroll
                for (int j = 0; j < 64; j += 4) {
                    float4 v = *(float4*)&t1l[o * 68 + j];
                    tr[j] = v.x; tr[j + 1] = v.y; tr[j + 2] = v.z; tr[j + 3] = v.w;
                }
#pragma unroll
                for (int pp = 0; pp < 4; ++pp) {
                    const float* br = &bdl[(p0 + pp) * 68];
                    float d = 0.f;
#pragma unroll
                    for (int j = 0; j < 64; j += 4) {
                        float4 b = *(float4*)&br[j];
                        d += b.x * tr[j] + b.y * tr[j + 1] + b.z * tr[j + 2] + b.w * tr[j + 3];
                    }
                    acc4[pp] += pw * d;
                }
            }
        }
        // epilogue: flat output index == tid*4 + pp (contiguous)
        {
            float vv[4];
#pragma unroll
            for (int z = 0; z < 4; ++z) vv[z] = acc4[z] * sc_dn + bias_dn[tid * 4 + z];
            *(float4*)&out[tok * 1024 + tid * 4] = make_float4(vv[0], vv[1], vv[2], vv[3]);
        }
    }
}

extern "C" void kernel_launch(void* const* d_in, const int* in_sizes, int n_in,
                              void* d_out, int out_size, void* d_ws, size_t ws_size,
                              hipStream_t stream) {
    const float* x   = (const float*)d_in[0];
    const float* Wup = (const float*)d_in[1];
    const float* Aup = (const float*)d_in[2];
    const float* Bup = (const float*)d_in[3];
    const float* scu = (const float*)d_in[4];
    const float* biu = (const float*)d_in[5];
    const float* Wdn = (const float*)d_in[6];
    const float* Adn = (const float*)d_in[7];
    const float* Bdn = (const float*)d_in[8];
    const float* scd = (const float*)d_in[9];
    const float* bid = (const float*)d_in[10];
    float* out = (float*)d_out;
    float* h   = (float*)d_ws;   // [N][4096] fp32 = 128 MB for N=8192

    const int N = in_sizes[0] / 1024;

    hipLaunchKernelGGL(up_kernel, dim3(N / TB1), dim3(256), 0, stream,
                       x, Wup, Aup, Bup, scu, biu, h);
    hipLaunchKernelGGL(down_kernel, dim3(N / TB2), dim3(256), 0, stream,
                       h, Wdn, Adn, Bdn, scd, bid, out);
}